// Round 2
// baseline (1742.906 us; speedup 1.0000x reference)
//
#include <hip/hip_runtime.h>
#include <math.h>

#define NNODES 262144      // B*N
#define NEDGE  2097152     // NNODES*DEG
#define NB     256         // graphs
#define NPG    1024        // nodes per graph
#define EPG    8192        // edges per graph
#define DF     128         // feature dim

typedef unsigned short u16;
typedef unsigned int   u32;

static constexpr int K1 = 820, K2 = 656, K3 = 525;

// ---- bf16 helpers (manual, RTNE) ----
__device__ inline float bflo(u32 u) { union { u32 i; float f; } c; c.i = u << 16;          return c.f; }
__device__ inline float bfhi(u32 u) { union { u32 i; float f; } c; c.i = u & 0xffff0000u;  return c.f; }
__device__ inline u32   f2bf(float f) {
  union { float f; u32 i; } c; c.f = f;
  const u32 r = c.i + 0x7fffu + ((c.i >> 16) & 1u);
  return r >> 16;
}

// ---------------- CSR build: counting sort edges by dst, per graph ----------------
__global__ __launch_bounds__(256) void build_csr_k(
    const int* __restrict__ ei, int* __restrict__ csr_src,
    int* __restrict__ row_off, int* __restrict__ row_cnt)
{
  __shared__ int cnt[NPG];
  __shared__ int roff[NPG];
  __shared__ int wsum[256];
  const int b = blockIdx.x, t = threadIdx.x;
  const int* src = ei;
  const int* dst = ei + NEDGE;
  const int e0 = b * EPG;
  for (int i = t; i < NPG; i += 256) cnt[i] = 0;
  __syncthreads();
  for (int e = t; e < EPG; e += 256) atomicAdd(&cnt[dst[e0 + e] & (NPG - 1)], 1);
  __syncthreads();
  const int c0 = cnt[t*4], c1 = cnt[t*4+1], c2 = cnt[t*4+2], c3 = cnt[t*4+3];
  const int s = c0 + c1 + c2 + c3;
  wsum[t] = s;
  __syncthreads();
  for (int off = 1; off < 256; off <<= 1) {
    int v = (t >= off) ? wsum[t - off] : 0;
    __syncthreads();
    wsum[t] += v;
    __syncthreads();
  }
  const int base = wsum[t] - s;   // exclusive prefix
  roff[t*4]   = base;
  roff[t*4+1] = base + c0;
  roff[t*4+2] = base + c0 + c1;
  roff[t*4+3] = base + c0 + c1 + c2;
  const int nb = b * NPG + t*4;
  row_off[nb]   = roff[t*4];   row_cnt[nb]   = c0;
  row_off[nb+1] = roff[t*4+1]; row_cnt[nb+1] = c1;
  row_off[nb+2] = roff[t*4+2]; row_cnt[nb+2] = c2;
  row_off[nb+3] = roff[t*4+3]; row_cnt[nb+3] = c3;
  __syncthreads();
  for (int e = t; e < EPG; e += 256) {
    const int dl = dst[e0 + e] & (NPG - 1);
    const int pos = atomicAdd(&roff[dl], 1);
    csr_src[e0 + pos] = src[e0 + e];   // store GLOBAL src node id
  }
}

// ---------------- Embedding gather (f32 -> bf16) + keep init ----------------
__global__ __launch_bounds__(256) void gather_k(
    const int* __restrict__ x_ids, const float* __restrict__ emb,
    u16* __restrict__ xh, float* __restrict__ keep)
{
  const int gid = blockIdx.x * 256 + threadIdx.x;  // NNODES*16 threads
  const int n = gid >> 4, c = gid & 15;
  const int id = x_ids[n];
  const float4 v0 = *(const float4*)(emb + (size_t)id * DF + c * 8);
  const float4 v1 = *(const float4*)(emb + (size_t)id * DF + c * 8 + 4);
  uint4 pk;
  pk.x = f2bf(v0.x) | (f2bf(v0.y) << 16);
  pk.y = f2bf(v0.z) | (f2bf(v0.w) << 16);
  pk.z = f2bf(v1.x) | (f2bf(v1.y) << 16);
  pk.w = f2bf(v1.z) | (f2bf(v1.w) << 16);
  *(uint4*)(xh + (size_t)n * DF + c * 8) = pk;
  if (c == 0) keep[n] = 1.0f;
}

// ---------------- Fused SAGE: CSR mean-aggregate + dual GEMM + relu + raw score ----
// tile: 64 nodes x 128 cols; 256 threads = 16 rows(x4 nodes) x 16 cols(x8 feats)
__global__ __launch_bounds__(256) void sage_k(
    const u16* __restrict__ xh, const float* __restrict__ keep,
    const int* __restrict__ csr_src, const int* __restrict__ row_off,
    const int* __restrict__ row_cnt,
    const float* __restrict__ Wl, const float* __restrict__ Wr,
    const float* __restrict__ bl, const float* __restrict__ p,
    u16* __restrict__ xnh, float* __restrict__ score)
{
  constexpr int PAD = 69;            // 64+5: GEMM-phase reads conflict-free
  __shared__ float a_t[64][PAD];     // agg tile, K-half at a time   [m][k]
  __shared__ float x_t[64][PAD];     // x tile, K-half at a time     [m][k]
  const int tid = threadIdx.x;
  // XCD swizzle: graph g's 16 blocks share blockIdx%8 -> same XCD L2
  const int bi  = blockIdx.x;
  const int g   = (bi & 7) + 8 * ((bi >> 3) >> 4);
  const int t16 = (bi >> 3) & 15;
  const int n0  = g * NPG + t16 * 64;

  // Phase B: aggregate this tile's 64 rows via CSR (regs, 32 feats/thread)
  const int nl = tid >> 2, q = tid & 3;      // node-local 0..63, k-quarter 0..3
  float bacc[32];
#pragma unroll
  for (int u = 0; u < 32; ++u) bacc[u] = 0.0f;
  {
    const int n   = n0 + nl;
    const int cnt = row_cnt[n];
    const int off = row_off[n];
    const int* ep = csr_src + g * EPG + off;
    float ks = 0.0f;
    for (int e = 0; e < cnt; ++e) {
      const int sidx = ep[e];
      ks += keep[sidx];
      const uint4* xr = (const uint4*)(xh + (size_t)sidx * DF + q * 32);
#pragma unroll
      for (int u = 0; u < 4; ++u) {
        const uint4 vv = xr[u];
        bacc[u*8+0] += bflo(vv.x); bacc[u*8+1] += bfhi(vv.x);
        bacc[u*8+2] += bflo(vv.y); bacc[u*8+3] += bfhi(vv.y);
        bacc[u*8+4] += bflo(vv.z); bacc[u*8+5] += bfhi(vv.z);
        bacc[u*8+6] += bflo(vv.w); bacc[u*8+7] += bfhi(vv.w);
      }
    }
    const float inv = 1.0f / fmaxf(ks, 1.0f);
#pragma unroll
    for (int u = 0; u < 32; ++u) bacc[u] *= inv;
  }

  const int col = tid & 15, row = tid >> 4;
  const float4* wl4 = (const float4*)(Wl + col * 8);
  const float4* wr4 = (const float4*)(Wr + col * 8);
  float acc[4][8];
#pragma unroll
  for (int ii = 0; ii < 4; ++ii)
#pragma unroll
    for (int j = 0; j < 8; ++j) acc[ii][j] = 0.0f;

  const int cs = tid & 15, rs = tid >> 4;   // staging decomposition
  for (int h = 0; h < 2; ++h) {
    // stage x half-tile [64][64] from bf16 rows
#pragma unroll
    for (int it = 0; it < 4; ++it) {
      const int m = rs + it * 16;
      const uint2 v = *(const uint2*)(xh + (size_t)(n0 + m) * DF + h * 64 + cs * 4);
      x_t[m][cs*4+0] = bflo(v.x); x_t[m][cs*4+1] = bfhi(v.x);
      x_t[m][cs*4+2] = bflo(v.y); x_t[m][cs*4+3] = bfhi(v.y);
    }
    // dump this thread's agg quarter if it belongs to half h
    if ((q >> 1) == h) {
      const int kb = (q & 1) * 32;
#pragma unroll
      for (int u = 0; u < 32; ++u) a_t[nl][kb + u] = bacc[u];
    }
    __syncthreads();
    // GEMM over this K-half
    const float* at0 = &a_t[row*4+0][0]; const float* xt0 = &x_t[row*4+0][0];
    const float* at1 = &a_t[row*4+1][0]; const float* xt1 = &x_t[row*4+1][0];
    const float* at2 = &a_t[row*4+2][0]; const float* xt2 = &x_t[row*4+2][0];
    const float* at3 = &a_t[row*4+3][0]; const float* xt3 = &x_t[row*4+3][0];
#pragma unroll 4
    for (int k = 0; k < 64; ++k) {
      const int kg = h * 64 + k;
      const float4 l0 = wl4[kg*32], l1 = wl4[kg*32+1];
      const float4 r0 = wr4[kg*32], r1 = wr4[kg*32+1];
      const float av[4] = {at0[k], at1[k], at2[k], at3[k]};
      const float bv[4] = {xt0[k], xt1[k], xt2[k], xt3[k]};
      const float wlv[8] = {l0.x,l0.y,l0.z,l0.w,l1.x,l1.y,l1.z,l1.w};
      const float wrv[8] = {r0.x,r0.y,r0.z,r0.w,r1.x,r1.y,r1.z,r1.w};
#pragma unroll
      for (int ii = 0; ii < 4; ++ii)
#pragma unroll
        for (int j = 0; j < 8; ++j)
          acc[ii][j] += av[ii]*wlv[j] + bv[ii]*wrv[j];
    }
    __syncthreads();
  }

  // Epilogue: +bias, relu, store xn (bf16), raw score (rank-invariant scaling)
  float blv[8], pv[8];
#pragma unroll
  for (int j = 0; j < 8; ++j) { blv[j] = bl[col*8+j]; pv[j] = p[col*8+j]; }
#pragma unroll
  for (int ii = 0; ii < 4; ++ii) {
    float o[8]; float si = 0.0f;
#pragma unroll
    for (int j = 0; j < 8; ++j) {
      float v = fmaxf(acc[ii][j] + blv[j], 0.0f);
      o[j] = v; si += v * pv[j];
    }
    uint4 pk;
    pk.x = f2bf(o[0]) | (f2bf(o[1]) << 16);
    pk.y = f2bf(o[2]) | (f2bf(o[3]) << 16);
    pk.z = f2bf(o[4]) | (f2bf(o[5]) << 16);
    pk.w = f2bf(o[6]) | (f2bf(o[7]) << 16);
    *(uint4*)(xnh + (size_t)(n0 + row*4 + ii) * DF + col * 8) = pk;
#pragma unroll
    for (int off = 1; off < 16; off <<= 1) si += __shfl_xor(si, off, 16);
    if (col == 0) score[n0 + row*4 + ii] = si;
  }
}

// ---------------- Per-graph top-k (exact argsort-rank) + scale + readout ----------
__global__ __launch_bounds__(256) void topk_k(
    const float* __restrict__ score, const float* __restrict__ p,
    const u16* __restrict__ xn, u16* __restrict__ xw,
    float* __restrict__ keep, float* __restrict__ xl, int K, int write_x)
{
  __shared__ float s_lds[NPG];
  __shared__ float fac[NPG];
  __shared__ float kfl[NPG];
  __shared__ float mxA[256], mxB[256], smA[256], smB[256];
  const int b = blockIdx.x, t = threadIdx.x;
  float ssq = 0.0f;
  for (int d = 0; d < DF; ++d) ssq += p[d] * p[d];
  const float inv_pn = 1.0f / sqrtf(ssq);
  const float NEG = -__builtin_huge_valf();
  for (int i = t; i < NPG; i += 256) {
    const int n = b * NPG + i;
    s_lds[i] = (keep[n] > 0.5f) ? score[n] : NEG;
  }
  __syncthreads();
  float si[4]; int rk[4] = {0,0,0,0};
#pragma unroll
  for (int ii = 0; ii < 4; ++ii) si[ii] = s_lds[t + 256*ii];
  for (int j = 0; j < NPG; ++j) {
    const float sj = s_lds[j];
#pragma unroll
    for (int ii = 0; ii < 4; ++ii) {
      const int idx = t + 256*ii;
      rk[ii] += (sj > si[ii]) || ((sj == si[ii]) && (j < idx));
    }
  }
#pragma unroll
  for (int ii = 0; ii < 4; ++ii) {
    const int i = t + 256*ii;
    const bool kp = rk[ii] < K;        // implies previously-active (inactive = -inf)
    keep[b*NPG + i] = kp ? 1.0f : 0.0f;
    kfl[i] = kp ? 1.0f : 0.0f;
    fac[i] = kp ? tanhf(si[ii] * inv_pn) : 0.0f;
  }
  __syncthreads();
  // scale x (bf16) and masked max/mean readout; thread owns d-pair, i-quarter
  const int dp = t & 63, qu = t >> 6;
  float mx0 = NEG, mx1 = NEG, sm0 = 0.0f, sm1 = 0.0f;
  for (int i = qu; i < NPG; i += 4) {
    const size_t base = ((size_t)(b*NPG + i)) * DF + dp * 2;
    const u32 u = *(const u32*)(xn + base);
    const float f = fac[i];
    const float v0 = bflo(u) * f, v1 = bfhi(u) * f;
    if (write_x) *(u32*)(xw + base) = f2bf(v0) | (f2bf(v1) << 16);
    if (kfl[i] > 0.5f) {
      mx0 = fmaxf(mx0, v0); mx1 = fmaxf(mx1, v1);
      sm0 += v0; sm1 += v1;
    }
  }
  mxA[t] = mx0; mxB[t] = mx1; smA[t] = sm0; smB[t] = sm1;
  __syncthreads();
  if (t < 64) {
    float m0 = mxA[t], m1 = mxB[t], s0 = smA[t], s1 = smB[t];
#pragma unroll
    for (int qq = 1; qq < 4; ++qq) {
      m0 = fmaxf(m0, mxA[qq*64 + t]); m1 = fmaxf(m1, mxB[qq*64 + t]);
      s0 += smA[qq*64 + t];           s1 += smB[qq*64 + t];
    }
    const int d0 = 2*t, d1 = 2*t + 1;
    const float invK = 1.0f / (float)K;
    xl[b*256 + d0]        = m0;
    xl[b*256 + d1]        = m1;
    xl[b*256 + 128 + d0]  = s0 * invK;
    xl[b*256 + 128 + d1]  = s1 * invK;
  }
}

// ---------------- Final MLP head, one block per graph ----------------
__global__ __launch_bounds__(256) void mlp_k(
    const float* __restrict__ xl,
    const float* __restrict__ W1, const float* __restrict__ b1,
    const float* __restrict__ W2, const float* __restrict__ b2,
    const float* __restrict__ W3, const float* __restrict__ b3,
    float* __restrict__ out)
{
  __shared__ float h0[256];
  __shared__ float h1[128];
  __shared__ float h2[64];
  const int b = blockIdx.x, t = threadIdx.x;
  h0[t] = xl[b*256 + t] + xl[(size_t)NB*256 + b*256 + t] + xl[(size_t)2*NB*256 + b*256 + t];
  __syncthreads();
  if (t < 128) {
    float a = b1[t];
    for (int k = 0; k < 256; ++k) a += h0[k] * W1[k*128 + t];
    h1[t] = fmaxf(a, 0.0f);
  }
  __syncthreads();
  if (t < 64) {
    float a = b2[t];
    for (int k = 0; k < 128; ++k) a += h1[k] * W2[k*64 + t];
    h2[t] = fmaxf(a, 0.0f);
  }
  __syncthreads();
  if (t < 64) {
    float v = h2[t] * W3[t];
#pragma unroll
    for (int off = 32; off > 0; off >>= 1) v += __shfl_xor(v, off, 64);
    if (t == 0) out[b] = 1.0f / (1.0f + expf(-(v + b3[0])));
  }
}

extern "C" void kernel_launch(void* const* d_in, const int* in_sizes, int n_in,
                              void* d_out, int out_size, void* d_ws, size_t ws_size,
                              hipStream_t stream)
{
  const int*   x_ids = (const int*)d_in[0];
  const int*   ei    = (const int*)d_in[1];
  const float* emb   = (const float*)d_in[3];
  const float* Wl[3]  = {(const float*)d_in[4],  (const float*)d_in[8],  (const float*)d_in[12]};
  const float* blv[3] = {(const float*)d_in[5],  (const float*)d_in[9],  (const float*)d_in[13]};
  const float* Wr[3]  = {(const float*)d_in[6],  (const float*)d_in[10], (const float*)d_in[14]};
  const float* pv[3]  = {(const float*)d_in[7],  (const float*)d_in[11], (const float*)d_in[15]};
  const float* W1 = (const float*)d_in[16]; const float* b1 = (const float*)d_in[17];
  const float* W2 = (const float*)d_in[18]; const float* b2 = (const float*)d_in[19];
  const float* W3 = (const float*)d_in[20]; const float* b3 = (const float*)d_in[21];

  char* ws = (char*)d_ws;
  size_t off = 0;
  auto alloc = [&](size_t bytes) -> void* {
    void* ptr = ws + off; off += (bytes + 255) & ~(size_t)255; return ptr;
  };
  u16*   xa    = (u16*)  alloc((size_t)NNODES * DF * 2);   // scaled features (sage input)
  u16*   xb    = (u16*)  alloc((size_t)NNODES * DF * 2);   // sage output
  float* score = (float*)alloc((size_t)NNODES * 4);
  float* keep  = (float*)alloc((size_t)NNODES * 4);
  int*   csr   = (int*)  alloc((size_t)NEDGE * 4);
  int*   roff  = (int*)  alloc((size_t)NNODES * 4);
  int*   rcnt  = (int*)  alloc((size_t)NNODES * 4);
  float* xl    = (float*)alloc((size_t)3 * NB * 256 * 4);
  (void)in_sizes; (void)n_in; (void)out_size;
  if (off > ws_size) return;   // graceful fail instead of OOB fault

  build_csr_k<<<NB, 256, 0, stream>>>(ei, csr, roff, rcnt);
  gather_k<<<NNODES * 16 / 256, 256, 0, stream>>>(x_ids, emb, xa, keep);
  const int Ks[3] = {K1, K2, K3};
  for (int l = 0; l < 3; ++l) {
    sage_k<<<NNODES / 64, 256, 0, stream>>>(xa, keep, csr, roff, rcnt,
                                            Wl[l], Wr[l], blv[l], pv[l], xb, score);
    topk_k<<<NB, 256, 0, stream>>>(score, pv[l], xb, xa, keep,
                                   xl + (size_t)l * NB * 256, Ks[l], l < 2 ? 1 : 0);
  }
  mlp_k<<<NB, 256, 0, stream>>>(xl, W1, b1, W2, b2, W3, b3, (float*)d_out);
}

// Round 3
// 1115.649 us; speedup vs baseline: 1.5622x; 1.5622x over previous
//
#include <hip/hip_runtime.h>
#include <math.h>

#define NNODES 262144      // B*N
#define NEDGE  2097152     // NNODES*DEG
#define NB     256         // graphs
#define NPG    1024        // nodes per graph
#define EPG    8192        // edges per graph
#define DF     128         // feature dim

typedef unsigned short u16;
typedef unsigned int   u32;
typedef __attribute__((ext_vector_type(8))) short  short8;   // 8 x bf16 (4 VGPRs)
typedef __attribute__((ext_vector_type(4))) float  floatx4;  // MFMA accumulator

static constexpr int K1 = 820, K2 = 656, K3 = 525;

// ---- bf16 helpers (manual, RTNE) ----
__device__ inline float bflo(u32 u) { union { u32 i; float f; } c; c.i = u << 16;          return c.f; }
__device__ inline float bfhi(u32 u) { union { u32 i; float f; } c; c.i = u & 0xffff0000u;  return c.f; }
__device__ inline u32   f2bf(float f) {
  union { float f; u32 i; } c; c.f = f;
  const u32 r = c.i + 0x7fffu + ((c.i >> 16) & 1u);
  return r >> 16;
}

// ---------------- CSR build: counting sort edges by dst, per graph ----------------
__global__ __launch_bounds__(256) void build_csr_k(
    const int* __restrict__ ei, int* __restrict__ csr_src,
    int* __restrict__ row_off, int* __restrict__ row_cnt)
{
  __shared__ int cnt[NPG];
  __shared__ int roff[NPG];
  __shared__ int wsum[256];
  const int b = blockIdx.x, t = threadIdx.x;
  const int* src = ei;
  const int* dst = ei + NEDGE;
  const int e0 = b * EPG;
  for (int i = t; i < NPG; i += 256) cnt[i] = 0;
  __syncthreads();
  for (int e = t; e < EPG; e += 256) atomicAdd(&cnt[dst[e0 + e] & (NPG - 1)], 1);
  __syncthreads();
  const int c0 = cnt[t*4], c1 = cnt[t*4+1], c2 = cnt[t*4+2], c3 = cnt[t*4+3];
  const int s = c0 + c1 + c2 + c3;
  wsum[t] = s;
  __syncthreads();
  for (int off = 1; off < 256; off <<= 1) {
    int v = (t >= off) ? wsum[t - off] : 0;
    __syncthreads();
    wsum[t] += v;
    __syncthreads();
  }
  const int base = wsum[t] - s;   // exclusive prefix
  roff[t*4]   = base;
  roff[t*4+1] = base + c0;
  roff[t*4+2] = base + c0 + c1;
  roff[t*4+3] = base + c0 + c1 + c2;
  const int nb = b * NPG + t*4;
  row_off[nb]   = roff[t*4];   row_cnt[nb]   = c0;
  row_off[nb+1] = roff[t*4+1]; row_cnt[nb+1] = c1;
  row_off[nb+2] = roff[t*4+2]; row_cnt[nb+2] = c2;
  row_off[nb+3] = roff[t*4+3]; row_cnt[nb+3] = c3;
  __syncthreads();
  for (int e = t; e < EPG; e += 256) {
    const int dl = dst[e0 + e] & (NPG - 1);
    const int pos = atomicAdd(&roff[dl], 1);
    csr_src[e0 + pos] = src[e0 + e];   // store GLOBAL src node id
  }
}

// ---------------- Embedding gather (f32 -> bf16) + keep/fac init ----------------
__global__ __launch_bounds__(256) void gather_k(
    const int* __restrict__ x_ids, const float* __restrict__ emb,
    u16* __restrict__ xh, float* __restrict__ keep, float* __restrict__ fac)
{
  const int gid = blockIdx.x * 256 + threadIdx.x;  // NNODES*16 threads
  const int n = gid >> 4, c = gid & 15;
  const int id = x_ids[n];
  const float4 v0 = *(const float4*)(emb + (size_t)id * DF + c * 8);
  const float4 v1 = *(const float4*)(emb + (size_t)id * DF + c * 8 + 4);
  uint4 pk;
  pk.x = f2bf(v0.x) | (f2bf(v0.y) << 16);
  pk.y = f2bf(v0.z) | (f2bf(v0.w) << 16);
  pk.z = f2bf(v1.x) | (f2bf(v1.y) << 16);
  pk.w = f2bf(v1.z) | (f2bf(v1.w) << 16);
  *(uint4*)(xh + (size_t)n * DF + c * 8) = pk;
  if (c == 0) { keep[n] = 1.0f; fac[n] = 1.0f; }
}

// ---------------- Weight pre-transpose+convert: wT[l][n][k] (bf16, K=256) --------
__global__ __launch_bounds__(256) void wcvt_k(
    const float* __restrict__ Wl1, const float* __restrict__ Wr1,
    const float* __restrict__ Wl2, const float* __restrict__ Wr2,
    const float* __restrict__ Wl3, const float* __restrict__ Wr3,
    u16* __restrict__ wT)
{
  const int l = blockIdx.x >> 7, n = blockIdx.x & 127, k = threadIdx.x;
  const float* Wl = (l == 0) ? Wl1 : (l == 1) ? Wl2 : Wl3;
  const float* Wr = (l == 0) ? Wr1 : (l == 1) ? Wr2 : Wr3;
  const float v = (k < 128) ? Wl[k * 128 + n] : Wr[(k - 128) * 128 + n];
  wT[(size_t)l * 32768 + n * 256 + k] = (u16)f2bf(v);
}

// ---------------- Fused SAGE: CSR mean-aggregate + bf16 MFMA dual GEMM ----------
// out = [agg | x*fac] @ [Wl ; Wr] + bl, relu, raw score.
// block = 256 thr (4 waves), tile = 64 nodes x 128 cols, K=256.
__global__ __launch_bounds__(256) void sage_k(
    const u16* __restrict__ xh, const float* __restrict__ keep,
    const float* __restrict__ fac,
    const int* __restrict__ csr_src, const int* __restrict__ row_off,
    const int* __restrict__ row_cnt,
    const u16* __restrict__ wT, const float* __restrict__ bl,
    const float* __restrict__ p,
    u16* __restrict__ xnh, float* __restrict__ score)
{
  // row stride 136 u16 = 272 B: MFMA-phase ds_read_b128 is 2-way (free)
  __shared__ u16 a_t[64 * 136];
  __shared__ u16 x_t[64 * 136];
  const int tid = threadIdx.x;
  const int bi  = blockIdx.x;
  const int g   = (bi & 7) + 8 * ((bi >> 3) >> 4);   // XCD swizzle
  const int t16 = (bi >> 3) & 15;
  const int n0  = g * NPG + t16 * 64;

  // ---- Phase A: aggregation (f32 regs; scaled by fac[src], deg = sum keep) ----
  const int nl = tid >> 2, q = tid & 3;      // node-local 0..63, feat-quarter 0..3
  float bacc[32];
#pragma unroll
  for (int u = 0; u < 32; ++u) bacc[u] = 0.0f;
  {
    const int n   = n0 + nl;
    const int cnt = row_cnt[n];
    const int off = row_off[n];
    const int* ep = csr_src + g * EPG + off;
    float ks = 0.0f;
    for (int e = 0; e < cnt; ++e) {
      const int sidx = ep[e];
      const float kf = keep[sidx];
      const float ff = fac[sidx];
      ks += kf;
      const uint4* xr = (const uint4*)(xh + (size_t)sidx * DF + q * 32);
#pragma unroll
      for (int u = 0; u < 4; ++u) {
        const uint4 vv = xr[u];
        bacc[u*8+0] += bflo(vv.x) * ff; bacc[u*8+1] += bfhi(vv.x) * ff;
        bacc[u*8+2] += bflo(vv.y) * ff; bacc[u*8+3] += bfhi(vv.y) * ff;
        bacc[u*8+4] += bflo(vv.z) * ff; bacc[u*8+5] += bfhi(vv.z) * ff;
        bacc[u*8+6] += bflo(vv.w) * ff; bacc[u*8+7] += bfhi(vv.w) * ff;
      }
    }
    const float inv = 1.0f / fmaxf(ks, 1.0f);
#pragma unroll
    for (int u = 0; u < 32; ++u) bacc[u] *= inv;
  }

  // ---- stage x*fac tile (bf16) ----
  {
    const int cs = tid & 15, rs = tid >> 4;
#pragma unroll
    for (int it = 0; it < 4; ++it) {
      const int m = rs + it * 16;
      const float fm = fac[n0 + m];
      const uint4 v = *(const uint4*)(xh + (size_t)(n0 + m) * DF + cs * 8);
      uint4 o;
      o.x = f2bf(bflo(v.x) * fm) | (f2bf(bfhi(v.x) * fm) << 16);
      o.y = f2bf(bflo(v.y) * fm) | (f2bf(bfhi(v.y) * fm) << 16);
      o.z = f2bf(bflo(v.z) * fm) | (f2bf(bfhi(v.z) * fm) << 16);
      o.w = f2bf(bflo(v.w) * fm) | (f2bf(bfhi(v.w) * fm) << 16);
      *(uint4*)(&x_t[m * 136 + cs * 8]) = o;
    }
  }
  // ---- dump agg tile (bf16) ----
  {
    u16* ar = &a_t[nl * 136 + q * 32];
#pragma unroll
    for (int i = 0; i < 4; ++i) {
      uint4 o;
      o.x = f2bf(bacc[i*8+0]) | (f2bf(bacc[i*8+1]) << 16);
      o.y = f2bf(bacc[i*8+2]) | (f2bf(bacc[i*8+3]) << 16);
      o.z = f2bf(bacc[i*8+4]) | (f2bf(bacc[i*8+5]) << 16);
      o.w = f2bf(bacc[i*8+6]) | (f2bf(bacc[i*8+7]) << 16);
      *(uint4*)(ar + i * 8) = o;
    }
  }
  __syncthreads();

  // ---- MFMA GEMM: wave wv -> rows m0..m0+15, all 128 cols, K=256 ----
  const int wv = tid >> 6, lane = tid & 63;
  const int lr = lane & 15, quad = lane >> 4;
  const int m0 = wv * 16;
  short8 af[8];
#pragma unroll
  for (int ks = 0; ks < 8; ++ks) {
    const u16* bp = ((ks < 4) ? a_t : x_t) + (m0 + lr) * 136 + (ks & 3) * 32 + quad * 8;
    af[ks] = *(const short8*)bp;
  }
  floatx4 acc[8];
#pragma unroll
  for (int ct = 0; ct < 8; ++ct) acc[ct] = (floatx4){0.f, 0.f, 0.f, 0.f};
#pragma unroll
  for (int ct = 0; ct < 8; ++ct) {
    const u16* wrow = wT + (ct * 16 + lr) * 256 + quad * 8;
#pragma unroll
    for (int ks = 0; ks < 8; ++ks) {
      const short8 bf = *(const short8*)(wrow + ks * 32);
      acc[ct] = __builtin_amdgcn_mfma_f32_16x16x32_bf16(af[ks], bf, acc[ct], 0, 0, 0);
    }
  }
  __syncthreads();

  // ---- epilogue: bias+relu, raw score, bf16 pack via LDS, coalesced store ----
  float si[4] = {0.f, 0.f, 0.f, 0.f};
#pragma unroll
  for (int ct = 0; ct < 8; ++ct) {
    const int n = ct * 16 + lr;
    const float bn = bl[n], pn = p[n];
#pragma unroll
    for (int r = 0; r < 4; ++r) {
      const float v = fmaxf(acc[ct][r] + bn, 0.0f);
      si[r] += v * pn;
      a_t[(m0 + quad * 4 + r) * 136 + n] = (u16)f2bf(v);
    }
  }
#pragma unroll
  for (int r = 0; r < 4; ++r) {
    float s = si[r];
#pragma unroll
    for (int off = 1; off < 16; off <<= 1) s += __shfl_xor(s, off, 16);
    if (lr == 0) score[n0 + m0 + quad * 4 + r] = s;
  }
  __syncthreads();
  {
    const int row = tid >> 2, ch = tid & 3;
#pragma unroll
    for (int i = 0; i < 4; ++i) {
      const uint4 vv = *(const uint4*)(&a_t[row * 136 + (ch * 4 + i) * 8]);
      *(uint4*)(xnh + (size_t)(n0 + row) * DF + (ch * 4 + i) * 8) = vv;
    }
  }
}

// ---------------- Per-graph top-k rank (exact argsort semantics) -> keep, fac ----
__global__ __launch_bounds__(256) void rank_k(
    const float* __restrict__ score, const float* __restrict__ p,
    float* __restrict__ keep, float* __restrict__ fac, int K)
{
  __shared__ float s_lds[NPG];
  const int b = blockIdx.x, t = threadIdx.x;
  float ssq = 0.0f;
  for (int d = 0; d < DF; ++d) ssq += p[d] * p[d];
  const float inv_pn = 1.0f / sqrtf(ssq);
  const float NEG = -__builtin_huge_valf();
  for (int i = t; i < NPG; i += 256) {
    const int n = b * NPG + i;
    s_lds[i] = (keep[n] > 0.5f) ? score[n] : NEG;
  }
  __syncthreads();
  float si[4]; int rk[4] = {0, 0, 0, 0};
#pragma unroll
  for (int ii = 0; ii < 4; ++ii) si[ii] = s_lds[t + 256 * ii];
  for (int j = 0; j < NPG; ++j) {
    const float sj = s_lds[j];
#pragma unroll
    for (int ii = 0; ii < 4; ++ii) {
      const int idx = t + 256 * ii;
      rk[ii] += (sj > si[ii]) || ((sj == si[ii]) && (j < idx));
    }
  }
#pragma unroll
  for (int ii = 0; ii < 4; ++ii) {
    const int n = b * NPG + t + 256 * ii;
    const bool kp = rk[ii] < K;   // implies previously-active (inactive = -inf)
    keep[n] = kp ? 1.0f : 0.0f;
    fac[n]  = kp ? tanhf(si[ii] * inv_pn) : 0.0f;
  }
}

// ---------------- Parallel masked readout: 4 blocks/graph -> partial max/sum ----
__global__ __launch_bounds__(256) void readout_k(
    const u16* __restrict__ feat, const float* __restrict__ fac,
    const float* __restrict__ keep, float* __restrict__ xlp)
{
  __shared__ float mxA[256], mxB[256], smA[256], smB[256];
  const int blk = blockIdx.x, b = blk >> 2, pr = blk & 3, t = threadIdx.x;
  const int d = t & 63, rq = t >> 6;
  const float NEG = -__builtin_huge_valf();
  float mx0 = NEG, mx1 = NEG, sm0 = 0.0f, sm1 = 0.0f;
  for (int j = 0; j < 64; ++j) {
    const int n = b * NPG + pr * 256 + rq + j * 4;
    const float kf = keep[n];
    const float f  = fac[n];
    const u32 u = *(const u32*)(feat + (size_t)n * DF + d * 2);
    const float v0 = bflo(u) * f, v1 = bfhi(u) * f;
    if (kf > 0.5f) {
      mx0 = fmaxf(mx0, v0); mx1 = fmaxf(mx1, v1);
      sm0 += v0; sm1 += v1;
    }
  }
  mxA[t] = mx0; mxB[t] = mx1; smA[t] = sm0; smB[t] = sm1;
  __syncthreads();
  if (t < 64) {
    float m0 = mxA[t], m1 = mxB[t], s0 = smA[t], s1 = smB[t];
#pragma unroll
    for (int qq = 1; qq < 4; ++qq) {
      m0 = fmaxf(m0, mxA[qq * 64 + t]); m1 = fmaxf(m1, mxB[qq * 64 + t]);
      s0 += smA[qq * 64 + t];           s1 += smB[qq * 64 + t];
    }
    float* o = xlp + (size_t)blk * 256;
    o[2 * t]           = m0;
    o[2 * t + 1]       = m1;
    o[128 + 2 * t]     = s0;
    o[128 + 2 * t + 1] = s1;
  }
}

// ---------------- Final MLP head, one block per graph ----------------
__global__ __launch_bounds__(256) void mlp_k(
    const float* __restrict__ xlp,
    const float* __restrict__ W1, const float* __restrict__ b1,
    const float* __restrict__ W2, const float* __restrict__ b2,
    const float* __restrict__ W3, const float* __restrict__ b3,
    float* __restrict__ out)
{
  __shared__ float h0[256];
  __shared__ float h1[128];
  __shared__ float h2[64];
  const int b = blockIdx.x, t = threadIdx.x;
  const float invK[3] = {1.0f / (float)K1, 1.0f / (float)K2, 1.0f / (float)K3};
  float v = 0.0f;
#pragma unroll
  for (int l = 0; l < 3; ++l) {
    const float* base = xlp + (size_t)l * NB * 1024 + (size_t)b * 1024;
    if (t < 128) {
      float m = base[t];
#pragma unroll
      for (int pr = 1; pr < 4; ++pr) m = fmaxf(m, base[pr * 256 + t]);
      v += m;
    } else {
      const float s = base[t] + base[256 + t] + base[512 + t] + base[768 + t];
      v += s * invK[l];
    }
  }
  h0[t] = v;
  __syncthreads();
  if (t < 128) {
    float a = b1[t];
    for (int k = 0; k < 256; ++k) a += h0[k] * W1[k * 128 + t];
    h1[t] = fmaxf(a, 0.0f);
  }
  __syncthreads();
  if (t < 64) {
    float a = b2[t];
    for (int k = 0; k < 128; ++k) a += h1[k] * W2[k * 64 + t];
    h2[t] = fmaxf(a, 0.0f);
  }
  __syncthreads();
  if (t < 64) {
    float vv = h2[t] * W3[t];
#pragma unroll
    for (int off = 32; off > 0; off >>= 1) vv += __shfl_xor(vv, off, 64);
    if (t == 0) out[b] = 1.0f / (1.0f + expf(-(vv + b3[0])));
  }
}

extern "C" void kernel_launch(void* const* d_in, const int* in_sizes, int n_in,
                              void* d_out, int out_size, void* d_ws, size_t ws_size,
                              hipStream_t stream)
{
  const int*   x_ids = (const int*)d_in[0];
  const int*   ei    = (const int*)d_in[1];
  const float* emb   = (const float*)d_in[3];
  const float* Wl[3]  = {(const float*)d_in[4],  (const float*)d_in[8],  (const float*)d_in[12]};
  const float* blv[3] = {(const float*)d_in[5],  (const float*)d_in[9],  (const float*)d_in[13]};
  const float* Wr[3]  = {(const float*)d_in[6],  (const float*)d_in[10], (const float*)d_in[14]};
  const float* pv[3]  = {(const float*)d_in[7],  (const float*)d_in[11], (const float*)d_in[15]};
  const float* W1 = (const float*)d_in[16]; const float* b1 = (const float*)d_in[17];
  const float* W2 = (const float*)d_in[18]; const float* b2 = (const float*)d_in[19];
  const float* W3 = (const float*)d_in[20]; const float* b3 = (const float*)d_in[21];

  char* ws = (char*)d_ws;
  size_t off = 0;
  auto alloc = [&](size_t bytes) -> void* {
    void* ptr = ws + off; off += (bytes + 255) & ~(size_t)255; return ptr;
  };
  u16*   fa    = (u16*)  alloc((size_t)NNODES * DF * 2);   // feature ping
  u16*   fb    = (u16*)  alloc((size_t)NNODES * DF * 2);   // feature pong
  float* score = (float*)alloc((size_t)NNODES * 4);
  float* keep  = (float*)alloc((size_t)NNODES * 4);
  float* fac   = (float*)alloc((size_t)NNODES * 4);
  int*   csr   = (int*)  alloc((size_t)NEDGE * 4);
  int*   roff  = (int*)  alloc((size_t)NNODES * 4);
  int*   rcnt  = (int*)  alloc((size_t)NNODES * 4);
  u16*   wT    = (u16*)  alloc((size_t)3 * 128 * 256 * 2);
  float* xlp   = (float*)alloc((size_t)3 * NB * 4 * 256 * 4);
  (void)in_sizes; (void)n_in; (void)out_size;
  if (off > ws_size) return;   // graceful fail instead of OOB fault

  wcvt_k<<<384, 256, 0, stream>>>(Wl[0], Wr[0], Wl[1], Wr[1], Wl[2], Wr[2], wT);
  build_csr_k<<<NB, 256, 0, stream>>>(ei, csr, roff, rcnt);
  gather_k<<<NNODES * 16 / 256, 256, 0, stream>>>(x_ids, emb, fa, keep, fac);
  const int Ks[3] = {K1, K2, K3};
  u16* fin = fa; u16* fout = fb;
  for (int l = 0; l < 3; ++l) {
    sage_k<<<NNODES / 64, 256, 0, stream>>>(fin, keep, fac, csr, roff, rcnt,
                                            wT + (size_t)l * 32768, blv[l], pv[l],
                                            fout, score);
    rank_k<<<NB, 256, 0, stream>>>(score, pv[l], keep, fac, Ks[l]);
    readout_k<<<NB * 4, 256, 0, stream>>>(fout, fac, keep,
                                          xlp + (size_t)l * NB * 1024);
    u16* tmp = fin; fin = fout; fout = tmp;
  }
  mlp_k<<<NB, 256, 0, stream>>>(xlp, W1, b1, W2, b2, W3, b3, (float*)d_out);
}